// Round 2
// 95.769 us; speedup vs baseline: 1.0036x; 1.0036x over previous
//
#include <hip/hip_runtime.h>
#include <math.h>

#define HIDDEN      128
#define TABLE_N     2048
#define SMAX        10.0f
#define E           4           // table entries per block (4 -> 512 blocks, 2 blocks/CU)
#define TB_THREADS  128         // one thread per hidden unit
#define MAIN_THREADS 256
#define EPS2        0.01f
#define MASS_EPS    1e-8f

// ---------------------------------------------------------------------------
// Kernel 1: tabulate g(s) = d/ds [ W3·silu(W2·silu(W1*s+b1)+b2) + b3 ]
// for s = t * SMAX/(TABLE_N-1), t = 0..TABLE_N-1.
// Each block computes E consecutive entries; thread tid owns hidden unit tid.
// E=4 / 512 blocks: 2 blocks/CU for latency hiding (was 1 block/CU at E=8).
// Tail reduce is a wave shfl tree (was: 4 lanes serially summing 128 values).
// ---------------------------------------------------------------------------
__global__ __launch_bounds__(TB_THREADS)
void build_table_kernel(const float* __restrict__ W1,
                        const float* __restrict__ b1,
                        const float* __restrict__ W2,
                        const float* __restrict__ b2,
                        const float* __restrict__ W3,
                        float* __restrict__ table)
{
    const int tid = threadIdx.x;            // hidden unit index 0..127
    const int e0  = blockIdx.x * E;         // first table entry of this block
    __shared__ float sh[HIDDEN * E];        // h1, then a
    __shared__ float wred[2 * E];           // per-wave reduce results

    const float ds  = SMAX / (float)(TABLE_N - 1);
    const float w1  = W1[tid];
    const float bb1 = b1[tid];

    // forward layer 1: h1 = silu(W1*s + b1), keep silu'(u1) in regs
    float sp1[E];
    #pragma unroll
    for (int e = 0; e < E; ++e) {
        float s  = (float)(e0 + e) * ds;
        float u1 = w1 * s + bb1;
        float sg = 1.0f / (1.0f + expf(-u1));
        sh[tid * E + e] = u1 * sg;                      // h1
        sp1[e] = sg * (1.0f + u1 * (1.0f - sg));        // silu'(u1)
    }
    __syncthreads();

    // forward layer 2: u2_i = b2_i + sum_j W2[i][j] h1_j (LDS broadcast reads)
    float u2[E];
    #pragma unroll
    for (int e = 0; e < E; ++e) u2[e] = b2[tid];
    #pragma unroll 4
    for (int j = 0; j < HIDDEN; ++j) {
        float w = W2[tid * HIDDEN + j];
        #pragma unroll
        for (int e = 0; e < E; ++e) u2[e] += w * sh[j * E + e];
    }

    // a_i = W3_i * silu'(u2_i)
    const float w3 = W3[tid];
    float a[E];
    #pragma unroll
    for (int e = 0; e < E; ++e) {
        float sg = 1.0f / (1.0f + expf(-u2[e]));
        a[e] = w3 * sg * (1.0f + u2[e] * (1.0f - sg));
    }
    __syncthreads();
    #pragma unroll
    for (int e = 0; e < E; ++e) sh[tid * E + e] = a[e];
    __syncthreads();

    // backward through W2: gv_j = sum_i W2[i][j] a_i (coalesced W2 column reads)
    float gv[E];
    #pragma unroll
    for (int e = 0; e < E; ++e) gv[e] = 0.0f;
    #pragma unroll 4
    for (int i = 0; i < HIDDEN; ++i) {
        float w = W2[i * HIDDEN + tid];
        #pragma unroll
        for (int e = 0; e < E; ++e) gv[e] += w * sh[i * E + e];
    }

    // partial_j = W1_j * silu'(u1_j) * gv_j ; reduce over j = 128 threads
    float part[E];
    #pragma unroll
    for (int e = 0; e < E; ++e) part[e] = w1 * sp1[e] * gv[e];

    // wave-level tree reduce (64 lanes), then combine the two waves via LDS
    #pragma unroll
    for (int e = 0; e < E; ++e) {
        #pragma unroll
        for (int off = 32; off > 0; off >>= 1)
            part[e] += __shfl_down(part[e], off, 64);
    }
    if ((tid & 63) == 0) {
        const int wave = tid >> 6;
        #pragma unroll
        for (int e = 0; e < E; ++e) wred[wave * E + e] = part[e];
    }
    __syncthreads();
    if (tid < E) table[e0 + tid] = wred[tid] + wred[E + tid];
}

// ---------------------------------------------------------------------------
// Kernel 2: streaming gradient field. One thread per sample.
// dqdt = p * minv ; dpdt accumulates g(s)*s^3*diff over the 3 pairs.
// LDS-staged loads/stores, vectorized as float4 (16 B/lane, G13).
// ---------------------------------------------------------------------------
__global__ __launch_bounds__(MAIN_THREADS)
void hnn_grad_kernel(const float* __restrict__ z,
                     const float* __restrict__ logm,
                     const float* __restrict__ table,
                     float* __restrict__ out)
{
    __shared__ __align__(16) float buf[MAIN_THREADS * 18];
    const int tid = threadIdx.x;
    const long long base = (long long)blockIdx.x * (MAIN_THREADS * 18);

    // coalesced global -> LDS stage: 1152 float4 per block (4.5/thread)
    const float4* __restrict__ zin = reinterpret_cast<const float4*>(z + base);
    float4* b4 = reinterpret_cast<float4*>(buf);
    #pragma unroll
    for (int k = 0; k < 4; ++k)
        b4[k * MAIN_THREADS + tid] = zin[k * MAIN_THREADS + tid];
    if (tid < MAIN_THREADS / 2)
        b4[4 * MAIN_THREADS + tid] = zin[4 * MAIN_THREADS + tid];
    __syncthreads();

    float q[9], p[9];
    #pragma unroll
    for (int c = 0; c < 9; ++c) q[c] = buf[tid * 18 + c];
    #pragma unroll
    for (int c = 0; c < 9; ++c) p[c] = buf[tid * 18 + 9 + c];

    const float minv0 = 1.0f / (expf(logm[0]) + MASS_EPS);
    const float minv1 = 1.0f / (expf(logm[1]) + MASS_EPS);
    const float minv2 = 1.0f / (expf(logm[2]) + MASS_EPS);

    float dq[9], dp[9];
    #pragma unroll
    for (int c = 0; c < 3; ++c) {
        dq[c]     = p[c]     * minv0;
        dq[3 + c] = p[3 + c] * minv1;
        dq[6 + c] = p[6 + c] * minv2;
    }
    #pragma unroll
    for (int c = 0; c < 9; ++c) dp[c] = 0.0f;

    const float scale = (float)(TABLE_N - 1) / SMAX;
    const int pi[3] = {0, 0, 1};
    const int pj[3] = {1, 2, 2};
    #pragma unroll
    for (int k = 0; k < 3; ++k) {
        const int i = pi[k] * 3, j = pj[k] * 3;
        float dx = q[i]     - q[j];
        float dy = q[i + 1] - q[j + 1];
        float dz = q[i + 2] - q[j + 2];
        float r2 = dx * dx + dy * dy + dz * dz + EPS2;
        float d  = sqrtf(r2);
        float s  = 1.0f / d;                // s <= 10
        // linear-interp table lookup of g(s) = dv/ds
        float x  = s * scale;
        int  idx = (int)x;
        idx = idx > (TABLE_N - 2) ? (TABLE_N - 2) : idx;
        float f  = x - (float)idx;
        float t0 = table[idx], t1 = table[idx + 1];
        float g  = t0 + f * (t1 - t0);
        // dpdt = -dV/dq ; dV/dq_i = -g*s^3*diff  => dp_i += g*s^3*diff
        float w = g * s * s * s;
        dp[i]     += w * dx;  dp[i + 1] += w * dy;  dp[i + 2] += w * dz;
        dp[j]     -= w * dx;  dp[j + 1] -= w * dy;  dp[j + 2] -= w * dz;
    }

    __syncthreads();   // all row-reads done before overwrite
    #pragma unroll
    for (int c = 0; c < 9; ++c) buf[tid * 18 + c]     = dq[c];
    #pragma unroll
    for (int c = 0; c < 9; ++c) buf[tid * 18 + 9 + c] = dp[c];
    __syncthreads();

    // coalesced LDS -> global store, float4
    float4* oout = reinterpret_cast<float4*>(out + base);
    #pragma unroll
    for (int k = 0; k < 4; ++k)
        oout[k * MAIN_THREADS + tid] = b4[k * MAIN_THREADS + tid];
    if (tid < MAIN_THREADS / 2)
        oout[4 * MAIN_THREADS + tid] = b4[4 * MAIN_THREADS + tid];
}

// ---------------------------------------------------------------------------
extern "C" void kernel_launch(void* const* d_in, const int* in_sizes, int n_in,
                              void* d_out, int out_size, void* d_ws, size_t ws_size,
                              hipStream_t stream)
{
    const float* z   = (const float*)d_in[0];   // (B, 18)
    const float* lm  = (const float*)d_in[1];   // (3,)
    const float* W1  = (const float*)d_in[2];   // (128,1) flat
    const float* b1  = (const float*)d_in[3];   // (128,)
    const float* W2  = (const float*)d_in[4];   // (128,128) row-major
    const float* b2  = (const float*)d_in[5];   // (128,)
    const float* W3  = (const float*)d_in[6];   // (1,128) flat
    // d_in[7] = b3: constant offset, zero gradient -> unused
    float* out   = (float*)d_out;
    float* table = (float*)d_ws;                // TABLE_N floats scratch

    hipLaunchKernelGGL(build_table_kernel, dim3(TABLE_N / E), dim3(TB_THREADS),
                       0, stream, W1, b1, W2, b2, W3, table);

    const int B = in_sizes[0] / 18;             // 262144
    hipLaunchKernelGGL(hnn_grad_kernel, dim3(B / MAIN_THREADS), dim3(MAIN_THREADS),
                       0, stream, z, lm, table, out);
}